// Round 11
// baseline (257.762 us; speedup 1.0000x reference)
//
#include <hip/hip_runtime.h>
#include <stdint.h>

typedef float  f32x4  __attribute__((ext_vector_type(4)));
typedef float  f32x16 __attribute__((ext_vector_type(16)));
typedef __bf16 bf16x8 __attribute__((ext_vector_type(8)));
typedef unsigned int   u32;
typedef unsigned int   u32x4v __attribute__((ext_vector_type(4)));
typedef unsigned short u16;

#define DEVI static __device__ __forceinline__

DEVI void gload16(void* lds, const void* g) {
  __builtin_amdgcn_global_load_lds((const __attribute__((address_space(1))) u32*)g,
                                   (__attribute__((address_space(3))) u32*)lds, 16, 0, 0);
}
DEVI f32x4 mfma16(bf16x8 a, bf16x8 b, f32x4 c) {
  return __builtin_amdgcn_mfma_f32_16x16x32_bf16(a, b, c, 0, 0, 0);
}
DEVI f32x16 mfma32(bf16x8 a, bf16x8 b, f32x16 c) {
  return __builtin_amdgcn_mfma_f32_32x32x16_bf16(a, b, c, 0, 0, 0);
}
DEVI u16 f2bf(float f) {  // RNE f32->bf16 (finite inputs)
  u32 u = __builtin_bit_cast(u32, f);
  return (u16)((u + 0x7FFFu + ((u >> 16) & 1u)) >> 16);
}
DEVI u32 cvtpk(float lo, float hi) {  // packed f32->bf16 pair, lo in [15:0]
  u32 r;
  asm("v_cvt_pk_bf16_f32 %0, %1, %2" : "=v"(r) : "v"(lo), "v"(hi));
  return r;
}
DEVI bf16x8 mkfrag(u32 a, u32 b, u32 c, u32 d) {
  u32x4v u = {a, b, c, d};
  return __builtin_bit_cast(bf16x8, u);
}
#if __has_builtin(__builtin_amdgcn_exp2f)
DEVI float exp2fast(float x) { return __builtin_amdgcn_exp2f(x); }
#else
DEVI float exp2fast(float x) { return exp2f(x); }
#endif

// ---------------- GroupNorm stats: one block per (b,g); 64ch*1024 = 65536 contiguous f32
__global__ __launch_bounds__(256) void k_gnstats(const float* __restrict__ x,
                                                 float* __restrict__ meanr) {
  const int bg = blockIdx.x;
  const float4* p4 = (const float4*)(x + (size_t)bg * 65536);
  const int t = threadIdx.x;
  float s = 0.f, ss = 0.f;
  for (int i = t; i < 16384; i += 256) {
    float4 v = p4[i];
    s  += v.x + v.y + v.z + v.w;
    ss += v.x*v.x + v.y*v.y + v.z*v.z + v.w*v.w;
  }
  for (int off = 32; off; off >>= 1) { s += __shfl_down(s, off); ss += __shfl_down(ss, off); }
  __shared__ float sa[4], sb[4];
  const int w = t >> 6;
  if ((t & 63) == 0) { sa[w] = s; sb[w] = ss; }
  __syncthreads();
  if (t == 0) {
    float S = sa[0]+sa[1]+sa[2]+sa[3], SS = sb[0]+sb[1]+sb[2]+sb[3];
    float mean = S * (1.f/65536.f);
    float var  = SS * (1.f/65536.f) - mean*mean;
    meanr[2*bg]   = mean;
    meanr[2*bg+1] = rsqrtf(var + 1e-5f);
  }
}

// ---------------- f32 -> bf16 weight convert
__global__ __launch_bounds__(256) void k_cvt(const float* __restrict__ a,
                                             u16* __restrict__ o, int n) {
  int i = blockIdx.x * 256 + threadIdx.x;
  const int stride = gridDim.x * 256;
  for (; i < n; i += stride) o[i] = f2bf(a[i]);
}

// ---------------- normalize + transpose: x[b][c][n] f32 -> xnT[b][n][c] bf16
__global__ __launch_bounds__(256) void k_norm_t(
    const float* __restrict__ x, const float* __restrict__ meanr,
    const float* __restrict__ scale, const float* __restrict__ bias,
    u16* __restrict__ xnT) {
  __shared__ __align__(16) char T[8192];   // [64 n][64 c] bf16, 16B-slot XOR swizzle
  const int t = threadIdx.x;
  const int nt = blockIdx.x, ct = blockIdx.y, b = blockIdx.z;
  const int n0 = nt*64, c0 = ct*64;
  const float mean = meanr[2*(b*8 + ct)];
  const float rstd = meanr[2*(b*8 + ct) + 1];
  const int n_l = t & 63;
  const float* xb = x + ((size_t)b*512 + c0)*1024 + n0;
  #pragma unroll
  for (int i = 0; i < 16; i++) {
    int c_l = i*4 + (t>>6);
    float xv = xb[(size_t)c_l*1024 + n_l];
    float val = (xv - mean)*rstd*scale[c0+c_l] + bias[c0+c_l];
    *(u16*)(T + n_l*128 + ((c_l*2) ^ ((n_l&7)<<4))) = f2bf(val);
  }
  __syncthreads();
  u16* outp = xnT + ((size_t)b*1024 + n0)*512 + c0;
  #pragma unroll
  for (int i = 0; i < 2; i++) {
    int idx = i*256 + t;
    int n_ = idx >> 3, s = idx & 7;
    uint4 val = *(const uint4*)(T + n_*128 + ((s ^ (n_&7))<<4));
    *(uint4*)((char*)outp + (size_t)n_*1024 + s*16) = val;
  }
}

// ---------------- GEMM: C[128m x 128n] = A[M][512] * Bt[n][512]^T, per-batch B
// 2-phase LDS double-buffer: stage(t+1) issued before compute(t); 1 barrier/step.
// MODE 0: qkv -> q/k transposed [b][h][n][64] (q scaled 1/8*log2e), v natural [b][h][64][n]
// MODE 1: proj -> out = C + bias + residual (f32)
template<int MODE>
__global__ __launch_bounds__(256) void k_gemm(
    const u16* __restrict__ A, const u16* __restrict__ Bt,
    const float* __restrict__ bias, const float* __restrict__ xres,
    u16* __restrict__ oq, u16* __restrict__ ok, u16* __restrict__ ov,
    float* __restrict__ out) {
  __shared__ __align__(16) char lds[65536];   // 2 x (A 16K | B 16K); epilogue reuses 32K
  const int t = threadIdx.x;
  const int wv = t >> 6, ln = t & 63;
  const int wr = wv >> 1, wc = wv & 1;
  const int b  = blockIdx.z;
  const int n0 = blockIdx.x * 128;
  const int m0 = blockIdx.y * 128;
  const u16* Bb = Bt + (size_t)b * (1024*512);

  f32x4 acc[4][4];
  #pragma unroll
  for (int i = 0; i < 4; i++)
    #pragma unroll
    for (int j = 0; j < 4; j++) acc[i][j] = f32x4{0.f,0.f,0.f,0.f};

  const int srow = ln >> 3, ssl = ln & 7;
  const int csw  = ssl ^ (srow & 7);          // pre-swizzled source slot

  auto stage = [&](int buf, int kb) {
    char* base = lds + (buf << 15);
    #pragma unroll
    for (int i = 0; i < 4; i++) {
      int row = wv*32 + i*8 + srow;
      gload16(base + (wv*32 + i*8)*128,
              (const char*)A  + ((size_t)(m0+row)*512 + kb*64)*2 + csw*16);
      gload16(base + 16384 + (wv*32 + i*8)*128,
              (const char*)Bb + ((size_t)(n0+row)*512 + kb*64)*2 + csw*16);
    }
  };

  stage(0, 0);
  __syncthreads();                            // buf0 staged (drains vmcnt)

  for (int kb = 0; kb < 8; kb++) {            // K = 512, BK = 64
    if (kb < 7) stage((kb + 1) & 1, kb + 1);  // issue next tile into other buf
    const char* cb = lds + ((kb & 1) << 15);
    #pragma unroll
    for (int kf = 0; kf < 2; kf++) {
      bf16x8 af[4], bfr[4];
      #pragma unroll
      for (int mi = 0; mi < 4; mi++) {
        int row = wr*64 + mi*16 + (ln & 15);
        af[mi] = *(const bf16x8*)(cb + row*128 + ((kf*64 + ((ln>>4)<<4)) ^ ((row&7)<<4)));
      }
      #pragma unroll
      for (int ni = 0; ni < 4; ni++) {
        int row = wc*64 + ni*16 + (ln & 15);
        bfr[ni] = *(const bf16x8*)(cb + 16384 + row*128 + ((kf*64 + ((ln>>4)<<4)) ^ ((row&7)<<4)));
      }
      __builtin_amdgcn_s_setprio(1);
      #pragma unroll
      for (int mi = 0; mi < 4; mi++)
        #pragma unroll
        for (int ni = 0; ni < 4; ni++)
          acc[mi][ni] = mfma16(af[mi], bfr[ni], acc[mi][ni]);
      __builtin_amdgcn_s_setprio(0);
    }
    __syncthreads();                          // next buf staged; cur buf free
  }

  if constexpr (MODE == 0) {
    if (m0 >= 1024) {                          // V: natural [b][512=h*64+d][1024]
      #pragma unroll
      for (int mi = 0; mi < 4; mi++) {
        #pragma unroll
        for (int r = 0; r < 4; r++) {
          int o_l = wr*64 + mi*16 + ((ln>>4)<<2) + r;
          float bia = bias[m0 + o_l];
          size_t rowoff = ((size_t)b*512 + (m0-1024) + o_l)*1024 + n0 + wc*64 + (ln & 15);
          #pragma unroll
          for (int ni = 0; ni < 4; ni++)
            ov[rowoff + ni*16] = f2bf(acc[mi][ni][r] + bia);
        }
      }
    } else {                                   // Q/K: transpose via LDS -> [b][h][n][64]
      const bool isq = (m0 < 512);
      const float sq = isq ? 0.18033688f : 1.0f;  // d^-0.5 * log2(e) folded into q
      u16* dstb = isq ? oq : ok;
      const int mloc = isq ? m0 : (m0 - 512);
      #pragma unroll
      for (int mi = 0; mi < 4; mi++) {
        #pragma unroll
        for (int r = 0; r < 4; r++) {
          int o_l = wr*64 + mi*16 + ((ln>>4)<<2) + r;
          float bia = bias[m0 + o_l];
          #pragma unroll
          for (int ni = 0; ni < 4; ni++) {
            int n_l = wc*64 + ni*16 + (ln & 15);
            *(u16*)(lds + n_l*256 + ((o_l*2) ^ ((n_l&7)<<4))) =
                f2bf((acc[mi][ni][r] + bia) * sq);
          }
        }
      }
      __syncthreads();
      const int h0 = mloc >> 6;                // 2 heads per 128-row tile
      #pragma unroll
      for (int i = 0; i < 8; i++) {
        int idx = i*256 + t;
        int n_ = idx >> 4, s = idx & 15;
        uint4 val = *(const uint4*)(lds + n_*256 + ((s ^ (n_&7))<<4));
        u16* dst = dstb + ((size_t)(b*8 + h0 + (s>>3))*1024 + (n0 + n_))*64 + (s&7)*8;
        *(uint4*)dst = val;
      }
    }
  } else {                                     // proj: + bias + residual, f32 out
    #pragma unroll
    for (int mi = 0; mi < 4; mi++) {
      #pragma unroll
      for (int r = 0; r < 4; r++) {
        int o_l = wr*64 + mi*16 + ((ln>>4)<<2) + r;
        float bia = bias[m0 + o_l];
        size_t rowoff = ((size_t)b*512 + m0 + o_l)*1024 + n0 + wc*64 + (ln & 15);
        #pragma unroll
        for (int ni = 0; ni < 4; ni++)
          out[rowoff + ni*16] = acc[mi][ni][r] + bia + xres[rowoff + ni*16];
      }
    }
  }
}

// ---------------- flash attention, swapped-QK^T 32x32 form, 8 waves.
// R11: each wave owns TWO 32-query sets (A: q0+l31, B: q0+32+l31) and every
// loaded K/V fragment feeds BOTH sets' MFMAs (qk_dual/pv_dual) — halves LDS
// read volume per FLOP (the R10 bottleneck). Block = 512 queries, grid.x = 2.
__global__ __launch_bounds__(512) void k_attn(
    const u16* __restrict__ qT, const u16* __restrict__ kT,
    const u16* __restrict__ v, u16* __restrict__ aoT) {
  __shared__ __align__(16) char lds[65536];    // 2 bufs x (K_A|K_B|V_A|V_B) x 8KB
  const int t = threadIdx.x, wv = t >> 6, ln = t & 63;
  const int l31 = ln & 31, hi = ln >> 5;
  const int qt = blockIdx.x, h = blockIdx.y, b = blockIdx.z;
  const size_t bh = (size_t)(b*8 + h);
  const int q0 = qt*512 + wv*64;
  const char* qp = (const char*)qT + (bh*1024 + q0)*128;
  const char* kp = (const char*)kT + bh*1024*128;
  const char* vp = (const char*)v  + bh*64*2048;

  const int srow = ln >> 3;
  const int csw16 = ((ln & 7) ^ srow) << 4;    // pre-swizzled source slot (bytes)
  const int rsw = (l31 & 7) << 4;              // read-side swizzle for this lane's rows
  const int grow = wv*8 + srow;                // this thread's staging row (0..63)

  auto stageChunk = [&](char* base, int mc) {  // one 128-key chunk (4 gload16/thread)
    gload16(base + wv*1024,         kp + (size_t)(mc*128 + grow)*128 + csw16);
    gload16(base + 8192 + wv*1024,  kp + (size_t)(mc*128 + 64 + grow)*128 + csw16);
    gload16(base + 16384 + wv*1024, vp + (size_t)grow*2048 + mc*256 + csw16);
    gload16(base + 24576 + wv*1024, vp + (size_t)grow*2048 + mc*256 + 128 + csw16);
  };

  // prologue: stage chunk 0 into buf 0
  stageChunk(lds, 0);

  bf16x8 qfA[4], qfB[4];                       // Q B-frags for both query sets
  #pragma unroll
  for (int ks = 0; ks < 4; ks++) {
    qfA[ks] = *(const bf16x8*)(qp + (size_t)l31*128 + ks*32 + hi*16);
    qfB[ks] = *(const bf16x8*)(qp + (size_t)(32 + l31)*128 + ks*32 + hi*16);
  }

  f32x16 oA0, oA1, oB0, oB1;                   // O^T accum for both sets
  #pragma unroll
  for (int i = 0; i < 16; i++) { oA0[i] = 0.f; oA1[i] = 0.f; oB0[i] = 0.f; oB1[i] = 0.f; }
  float MA = -1e30f, LA = 0.f, MB = -1e30f, LB = 0.f;  // L own-half partials

  // QK^T for one 64-key half, both query sets off shared K frags
  auto qk_dual = [&](const char* Kl, f32x16& a0, f32x16& a1, f32x16& b0, f32x16& b1) {
    #pragma unroll
    for (int i = 0; i < 16; i++) { a0[i] = 0.f; a1[i] = 0.f; b0[i] = 0.f; b1[i] = 0.f; }
    __builtin_amdgcn_s_setprio(1);
    #pragma unroll
    for (int ks = 0; ks < 4; ks++) {
      int col = (ks*32 + hi*16) ^ rsw;
      bf16x8 k0 = *(const bf16x8*)(Kl + (size_t)l31*128 + col);
      bf16x8 k1 = *(const bf16x8*)(Kl + (size_t)(32 + l31)*128 + col);
      a0 = mfma32(k0, qfA[ks], a0);
      a1 = mfma32(k1, qfA[ks], a1);
      b0 = mfma32(k0, qfB[ks], b0);
      b1 = mfma32(k1, qfB[ks], b1);
    }
    __builtin_amdgcn_s_setprio(0);
  };

  // softmax + P->bf16 frags for one (set, half): updates M, L, rescales o
  auto sm = [&](f32x16& s0, f32x16& s1, float& M, float& L,
                f32x16& o0, f32x16& o1, bf16x8* pf) {
    float m8[8];
    #pragma unroll
    for (int i = 0; i < 8; i++)
      m8[i] = fmaxf(fmaxf(s0[2*i], s0[2*i+1]), fmaxf(s1[2*i], s1[2*i+1]));
    float m4a = fmaxf(m8[0], m8[1]), m4b = fmaxf(m8[2], m8[3]);
    float m4c = fmaxf(m8[4], m8[5]), m4d = fmaxf(m8[6], m8[7]);
    float cm = fmaxf(fmaxf(m4a, m4b), fmaxf(m4c, m4d));
    cm = fmaxf(cm, __shfl_xor(cm, 32));
    if (!__all(cm <= M + 11.f)) {              // defer-max: P bounded by 2^11
      float nm = fmaxf(M, cm);
      float al = exp2fast(M - nm);
      M = nm;
      #pragma unroll
      for (int i = 0; i < 16; i++) { o0[i] *= al; o1[i] *= al; }
      L *= al;
    }
    #pragma unroll
    for (int i = 0; i < 16; i++) {
      s0[i] = exp2fast(s0[i] - M);
      s1[i] = exp2fast(s1[i] - M);
    }
    float r8[8];
    #pragma unroll
    for (int i = 0; i < 8; i++)
      r8[i] = (s0[2*i] + s0[2*i+1]) + (s1[2*i] + s1[2*i+1]);
    float r4a = r8[0] + r8[1], r4b = r8[2] + r8[3];
    float r4c = r8[4] + r8[5], r4d = r8[6] + r8[7];
    L += (r4a + r4b) + (r4c + r4d);            // own-half partial only

    u32 x0 = cvtpk(s0[0],  s0[1]),  x1 = cvtpk(s0[2],  s0[3]);
    u32 x2 = cvtpk(s0[4],  s0[5]),  x3 = cvtpk(s0[6],  s0[7]);
    u32 x4 = cvtpk(s0[8],  s0[9]),  x5 = cvtpk(s0[10], s0[11]);
    u32 x6 = cvtpk(s0[12], s0[13]), x7 = cvtpk(s0[14], s0[15]);
    u32 y0 = cvtpk(s1[0],  s1[1]),  y1 = cvtpk(s1[2],  s1[3]);
    u32 y2 = cvtpk(s1[4],  s1[5]),  y3 = cvtpk(s1[6],  s1[7]);
    u32 y4 = cvtpk(s1[8],  s1[9]),  y5 = cvtpk(s1[10], s1[11]);
    u32 y6 = cvtpk(s1[12], s1[13]), y7 = cvtpk(s1[14], s1[15]);
    // packed one-direction exchange (R10-proven)
    u32 e0 = (u32)__shfl_xor((int)(hi ? x0 : x2), 32);
    u32 e1 = (u32)__shfl_xor((int)(hi ? x1 : x3), 32);
    u32 e2 = (u32)__shfl_xor((int)(hi ? x4 : x6), 32);
    u32 e3 = (u32)__shfl_xor((int)(hi ? x5 : x7), 32);
    u32 f0 = (u32)__shfl_xor((int)(hi ? y0 : y2), 32);
    u32 f1 = (u32)__shfl_xor((int)(hi ? y1 : y3), 32);
    u32 f2 = (u32)__shfl_xor((int)(hi ? y4 : y6), 32);
    u32 f3 = (u32)__shfl_xor((int)(hi ? y5 : y7), 32);
    pf[0] = hi ? mkfrag(e0, e1, x2, x3) : mkfrag(x0, x1, e0, e1);
    pf[1] = hi ? mkfrag(e2, e3, x6, x7) : mkfrag(x4, x5, e2, e3);
    pf[2] = hi ? mkfrag(f0, f1, y2, y3) : mkfrag(y0, y1, f0, f1);
    pf[3] = hi ? mkfrag(f2, f3, y6, y7) : mkfrag(y4, y5, f2, f3);
  };

  auto pv_dual = [&](const char* Vl, const bf16x8* pfA, const bf16x8* pfB) {
    __builtin_amdgcn_s_setprio(1);
    #pragma unroll
    for (int s = 0; s < 4; s++) {
      int col = (s*32 + hi*16) ^ rsw;
      bf16x8 v0 = *(const bf16x8*)(Vl + (size_t)l31*128 + col);
      bf16x8 v1 = *(const bf16x8*)(Vl + (size_t)(32 + l31)*128 + col);
      oA0 = mfma32(v0, pfA[s], oA0);
      oA1 = mfma32(v1, pfA[s], oA1);
      oB0 = mfma32(v0, pfB[s], oB0);
      oB1 = mfma32(v1, pfB[s], oB1);
    }
    __builtin_amdgcn_s_setprio(0);
  };

  __syncthreads();                             // chunk 0 staged (drains vmcnt)

  for (int mc = 0; mc < 8; mc++) {             // 8 rounds of 128 keys
    char* cb = lds + ((mc & 1) << 15);
    if (mc < 7) stageChunk(lds + (((mc + 1) & 1) << 15), mc + 1);
    #pragma unroll
    for (int half = 0; half < 2; half++) {     // two 64-key bodies per round
      const char* Kl = cb + half*8192;
      const char* Vl = cb + 16384 + half*8192;
      f32x16 sa0, sa1, sb0, sb1;
      bf16x8 pfA[4], pfB[4];
      qk_dual(Kl, sa0, sa1, sb0, sb1);
      sm(sa0, sa1, MA, LA, oA0, oA1, pfA);
      sm(sb0, sb1, MB, LB, oB0, oB1, pfB);
      pv_dual(Vl, pfA, pfB);
    }
    __syncthreads();                           // releases cur buf, publishes next buf
  }

  // ---- epilogue: merge cross-half L, then O/L -> aoT[b][n][c=h*64+d] bf16 ----
  LA += __shfl_xor(LA, 32);
  LB += __shfl_xor(LB, 32);
  float invA = 1.f / LA, invB = 1.f / LB;
  u16* dstA = aoT + ((size_t)(b*1024 + q0 + l31))*512 + h*64;
  u16* dstB = dstA + 32*512;
  #pragma unroll
  for (int qd = 0; qd < 4; qd++) {
    uint2 val;
    val.x = cvtpk(oA0[4*qd+0]*invA, oA0[4*qd+1]*invA);
    val.y = cvtpk(oA0[4*qd+2]*invA, oA0[4*qd+3]*invA);
    *(uint2*)(dstA + qd*8 + hi*4) = val;
    val.x = cvtpk(oA1[4*qd+0]*invA, oA1[4*qd+1]*invA);
    val.y = cvtpk(oA1[4*qd+2]*invA, oA1[4*qd+3]*invA);
    *(uint2*)(dstA + 32 + qd*8 + hi*4) = val;
    val.x = cvtpk(oB0[4*qd+0]*invB, oB0[4*qd+1]*invB);
    val.y = cvtpk(oB0[4*qd+2]*invB, oB0[4*qd+3]*invB);
    *(uint2*)(dstB + qd*8 + hi*4) = val;
    val.x = cvtpk(oB1[4*qd+0]*invB, oB1[4*qd+1]*invB);
    val.y = cvtpk(oB1[4*qd+2]*invB, oB1[4*qd+3]*invB);
    *(uint2*)(dstB + 32 + qd*8 + hi*4) = val;
  }
}

extern "C" void kernel_launch(void* const* d_in, const int* in_sizes, int n_in,
                              void* d_out, int out_size, void* d_ws, size_t ws_size,
                              hipStream_t stream) {
  const float* x     = (const float*)d_in[0];
  const float* nsc   = (const float*)d_in[1];
  const float* nbi   = (const float*)d_in[2];
  const float* qkvw  = (const float*)d_in[3];
  const float* qkvb  = (const float*)d_in[4];
  const float* projw = (const float*)d_in[5];
  const float* projb = (const float*)d_in[6];
  float* out = (float*)d_out;

  char* ws = (char*)d_ws;
  float* meanr = (float*)ws;                          // 2 KB
  u16* qkvwb  = (u16*)(ws + 2048);                    // 1536*512*2
  u16* projwb = (u16*)(ws + 2048 + 1572864);          // 512*512*2
  char* p = ws + 2048 + 1572864 + 524288;
  u16* qT  = (u16*)p; p += 33554432;                  // [b][h][1024][64] bf16 (scaled)
  u16* kTb = (u16*)p; p += 33554432;                  // [b][h][1024][64] bf16
  u16* vb  = (u16*)p; p += 33554432;                  // [b][h][64][1024] bf16
  u16* xnT = (u16*)p;                                 // [b][1024][512] bf16, reused as aoT
  u16* aoT = xnT;

  k_gnstats<<<256, 256, 0, stream>>>(x, meanr);
  k_cvt<<<768, 256, 0, stream>>>(qkvw, qkvwb, 1536*512);
  k_cvt<<<256, 256, 0, stream>>>(projw, projwb, 512*512);
  k_norm_t<<<dim3(16, 8, 32), 256, 0, stream>>>(x, meanr, nsc, nbi, xnT);
  k_gemm<0><<<dim3(8, 12, 32), 256, 0, stream>>>(qkvwb, xnT, qkvb, nullptr,
                                                 qT, kTb, vb, nullptr);
  k_attn<<<dim3(2, 8, 32), 512, 0, stream>>>(qT, kTb, vb, aoT);
  k_gemm<1><<<dim3(8, 4, 32), 256, 0, stream>>>(projwb, aoT, projb, x,
                                                nullptr, nullptr, nullptr, out);
}

// Round 12
// 236.869 us; speedup vs baseline: 1.0882x; 1.0882x over previous
//
#include <hip/hip_runtime.h>
#include <stdint.h>

typedef float  f32x4  __attribute__((ext_vector_type(4)));
typedef float  f32x16 __attribute__((ext_vector_type(16)));
typedef __bf16 bf16x8 __attribute__((ext_vector_type(8)));
typedef unsigned int   u32;
typedef unsigned int   u32x4v __attribute__((ext_vector_type(4)));
typedef unsigned short u16;

#define DEVI static __device__ __forceinline__

DEVI void gload16(void* lds, const void* g) {
  __builtin_amdgcn_global_load_lds((const __attribute__((address_space(1))) u32*)g,
                                   (__attribute__((address_space(3))) u32*)lds, 16, 0, 0);
}
DEVI f32x4 mfma16(bf16x8 a, bf16x8 b, f32x4 c) {
  return __builtin_amdgcn_mfma_f32_16x16x32_bf16(a, b, c, 0, 0, 0);
}
DEVI f32x16 mfma32(bf16x8 a, bf16x8 b, f32x16 c) {
  return __builtin_amdgcn_mfma_f32_32x32x16_bf16(a, b, c, 0, 0, 0);
}
DEVI u16 f2bf(float f) {  // RNE f32->bf16 (finite inputs)
  u32 u = __builtin_bit_cast(u32, f);
  return (u16)((u + 0x7FFFu + ((u >> 16) & 1u)) >> 16);
}
DEVI u32 cvtpk(float lo, float hi) {  // packed f32->bf16 pair, lo in [15:0]
  u32 r;
  asm("v_cvt_pk_bf16_f32 %0, %1, %2" : "=v"(r) : "v"(lo), "v"(hi));
  return r;
}
DEVI bf16x8 mkfrag(u32 a, u32 b, u32 c, u32 d) {
  u32x4v u = {a, b, c, d};
  return __builtin_bit_cast(bf16x8, u);
}
#if __has_builtin(__builtin_amdgcn_exp2f)
DEVI float exp2fast(float x) { return __builtin_amdgcn_exp2f(x); }
#else
DEVI float exp2fast(float x) { return exp2f(x); }
#endif

// ---------------- fused GroupNorm stats + normalize + transpose.
// One block per (g,b): stats over the group's contiguous 64ch x 1024 f32
// (256 KB, HBM), then re-read (L2-hot) to normalize + transpose -> xnT bf16.
// Saves one full HBM pass of x vs separate gnstats + norm_t kernels.
__global__ __launch_bounds__(1024) void k_gn_norm_t(
    const float* __restrict__ x, const float* __restrict__ scale,
    const float* __restrict__ bias, u16* __restrict__ xnT) {
  const int g = blockIdx.x, b = blockIdx.y;
  const float* xg = x + ((size_t)(b*8 + g)) * 65536;   // x[b][g*64..][0..1023]
  const int t = threadIdx.x;

  // ---- stats pass: 16384 float4, 1024 threads x 16 ----
  float s = 0.f, ss = 0.f;
  const float4* p4 = (const float4*)xg;
  #pragma unroll
  for (int i = 0; i < 16; i++) {
    float4 v = p4[t + i*1024];
    s  += v.x + v.y + v.z + v.w;
    ss += v.x*v.x + v.y*v.y + v.z*v.z + v.w*v.w;
  }
  #pragma unroll
  for (int off = 32; off; off >>= 1) { s += __shfl_down(s, off); ss += __shfl_down(ss, off); }
  __shared__ float sa[16], sb[16];
  __shared__ float stats[2];
  if ((t & 63) == 0) { sa[t >> 6] = s; sb[t >> 6] = ss; }
  __syncthreads();
  if (t == 0) {
    float S = 0.f, SS = 0.f;
    #pragma unroll
    for (int i = 0; i < 16; i++) { S += sa[i]; SS += sb[i]; }
    float mean = S * (1.f/65536.f);
    float var  = SS * (1.f/65536.f) - mean*mean;
    stats[0] = mean;
    stats[1] = rsqrtf(var + 1e-5f);
  }
  __syncthreads();
  const float mean = stats[0], rstd = stats[1];

  // ---- normalize + transpose: 16 n-tiles, 4 tiles in flight (4 x 256-thread groups)
  __shared__ __align__(16) char T[4][8192];    // [64 n][64 c] bf16, swizzled
  const int grp = t >> 8, lt = t & 255;
  const int n_l = lt & 63;
  for (int it = 0; it < 4; it++) {
    const int n0 = (it*4 + grp) * 64;
    #pragma unroll
    for (int i = 0; i < 16; i++) {
      int c_l = i*4 + (lt >> 6);
      float xv = xg[(size_t)c_l*1024 + n0 + n_l];  // L2-hot re-read
      float val = (xv - mean)*rstd*scale[g*64 + c_l] + bias[g*64 + c_l];
      *(u16*)(T[grp] + n_l*128 + ((c_l*2) ^ ((n_l&7)<<4))) = f2bf(val);
    }
    __syncthreads();
    u16* outp = xnT + ((size_t)b*1024 + n0)*512 + g*64;
    #pragma unroll
    for (int i = 0; i < 2; i++) {
      int idx = i*256 + lt;
      int n_ = idx >> 3, sl = idx & 7;
      uint4 val = *(const uint4*)(T[grp] + n_*128 + ((sl ^ (n_&7))<<4));
      *(uint4*)((char*)outp + (size_t)n_*1024 + sl*16) = val;
    }
    __syncthreads();
  }
}

// ---------------- f32 -> bf16 weight convert
__global__ __launch_bounds__(256) void k_cvt(const float* __restrict__ a,
                                             u16* __restrict__ o, int n) {
  int i = blockIdx.x * 256 + threadIdx.x;
  const int stride = gridDim.x * 256;
  for (; i < n; i += stride) o[i] = f2bf(a[i]);
}

// ---------------- GEMM: C[128m x 128n] = A[M][512] * Bt[n][512]^T, per-batch B
// 2-phase LDS double-buffer: stage(t+1) issued before compute(t); 1 barrier/step.
// MODE 0: qkv -> q/k transposed [b][h][n][64] (q scaled 1/8*log2e), v natural [b][h][64][n]
// MODE 1: proj -> out = C + bias + residual (f32)
template<int MODE>
__global__ __launch_bounds__(256) void k_gemm(
    const u16* __restrict__ A, const u16* __restrict__ Bt,
    const float* __restrict__ bias, const float* __restrict__ xres,
    u16* __restrict__ oq, u16* __restrict__ ok, u16* __restrict__ ov,
    float* __restrict__ out) {
  __shared__ __align__(16) char lds[65536];   // 2 x (A 16K | B 16K); epilogue reuses 32K
  const int t = threadIdx.x;
  const int wv = t >> 6, ln = t & 63;
  const int wr = wv >> 1, wc = wv & 1;
  const int b  = blockIdx.z;
  const int n0 = blockIdx.x * 128;
  const int m0 = blockIdx.y * 128;
  const u16* Bb = Bt + (size_t)b * (1024*512);

  f32x4 acc[4][4];
  #pragma unroll
  for (int i = 0; i < 4; i++)
    #pragma unroll
    for (int j = 0; j < 4; j++) acc[i][j] = f32x4{0.f,0.f,0.f,0.f};

  const int srow = ln >> 3, ssl = ln & 7;
  const int csw  = ssl ^ (srow & 7);          // pre-swizzled source slot

  auto stage = [&](int buf, int kb) {
    char* base = lds + (buf << 15);
    #pragma unroll
    for (int i = 0; i < 4; i++) {
      int row = wv*32 + i*8 + srow;
      gload16(base + (wv*32 + i*8)*128,
              (const char*)A  + ((size_t)(m0+row)*512 + kb*64)*2 + csw*16);
      gload16(base + 16384 + (wv*32 + i*8)*128,
              (const char*)Bb + ((size_t)(n0+row)*512 + kb*64)*2 + csw*16);
    }
  };

  stage(0, 0);
  __syncthreads();                            // buf0 staged (drains vmcnt)

  for (int kb = 0; kb < 8; kb++) {            // K = 512, BK = 64
    if (kb < 7) stage((kb + 1) & 1, kb + 1);  // issue next tile into other buf
    const char* cb = lds + ((kb & 1) << 15);
    #pragma unroll
    for (int kf = 0; kf < 2; kf++) {
      bf16x8 af[4], bfr[4];
      #pragma unroll
      for (int mi = 0; mi < 4; mi++) {
        int row = wr*64 + mi*16 + (ln & 15);
        af[mi] = *(const bf16x8*)(cb + row*128 + ((kf*64 + ((ln>>4)<<4)) ^ ((row&7)<<4)));
      }
      #pragma unroll
      for (int ni = 0; ni < 4; ni++) {
        int row = wc*64 + ni*16 + (ln & 15);
        bfr[ni] = *(const bf16x8*)(cb + 16384 + row*128 + ((kf*64 + ((ln>>4)<<4)) ^ ((row&7)<<4)));
      }
      __builtin_amdgcn_s_setprio(1);
      #pragma unroll
      for (int mi = 0; mi < 4; mi++)
        #pragma unroll
        for (int ni = 0; ni < 4; ni++)
          acc[mi][ni] = mfma16(af[mi], bfr[ni], acc[mi][ni]);
      __builtin_amdgcn_s_setprio(0);
    }
    __syncthreads();                          // next buf staged; cur buf free
  }

  if constexpr (MODE == 0) {
    if (m0 >= 1024) {                          // V: natural [b][512=h*64+d][1024]
      #pragma unroll
      for (int mi = 0; mi < 4; mi++) {
        #pragma unroll
        for (int r = 0; r < 4; r++) {
          int o_l = wr*64 + mi*16 + ((ln>>4)<<2) + r;
          float bia = bias[m0 + o_l];
          size_t rowoff = ((size_t)b*512 + (m0-1024) + o_l)*1024 + n0 + wc*64 + (ln & 15);
          #pragma unroll
          for (int ni = 0; ni < 4; ni++)
            ov[rowoff + ni*16] = f2bf(acc[mi][ni][r] + bia);
        }
      }
    } else {                                   // Q/K: transpose via LDS -> [b][h][n][64]
      const bool isq = (m0 < 512);
      const float sq = isq ? 0.18033688f : 1.0f;  // d^-0.5 * log2(e) folded into q
      u16* dstb = isq ? oq : ok;
      const int mloc = isq ? m0 : (m0 - 512);
      #pragma unroll
      for (int mi = 0; mi < 4; mi++) {
        #pragma unroll
        for (int r = 0; r < 4; r++) {
          int o_l = wr*64 + mi*16 + ((ln>>4)<<2) + r;
          float bia = bias[m0 + o_l];
          #pragma unroll
          for (int ni = 0; ni < 4; ni++) {
            int n_l = wc*64 + ni*16 + (ln & 15);
            *(u16*)(lds + n_l*256 + ((o_l*2) ^ ((n_l&7)<<4))) =
                f2bf((acc[mi][ni][r] + bia) * sq);
          }
        }
      }
      __syncthreads();
      const int h0 = mloc >> 6;                // 2 heads per 128-row tile
      #pragma unroll
      for (int i = 0; i < 8; i++) {
        int idx = i*256 + t;
        int n_ = idx >> 4, s = idx & 15;
        uint4 val = *(const uint4*)(lds + n_*256 + ((s ^ (n_&7))<<4));
        u16* dst = dstb + ((size_t)(b*8 + h0 + (s>>3))*1024 + (n0 + n_))*64 + (s&7)*8;
        *(uint4*)dst = val;
      }
    }
  } else {                                     // proj: + bias + residual, f32 out
    #pragma unroll
    for (int mi = 0; mi < 4; mi++) {
      #pragma unroll
      for (int r = 0; r < 4; r++) {
        int o_l = wr*64 + mi*16 + ((ln>>4)<<2) + r;
        float bia = bias[m0 + o_l];
        size_t rowoff = ((size_t)b*512 + m0 + o_l)*1024 + n0 + wc*64 + (ln & 15);
        #pragma unroll
        for (int ni = 0; ni < 4; ni++)
          out[rowoff + ni*16] = acc[mi][ni][r] + bia + xres[rowoff + ni*16];
      }
    }
  }
}

// ---------------- flash attention (R10-proven, reverted verbatim).
// swapped-QK^T 32x32 form, 8 waves, 128-key rounds, packed one-direction
// P-exchange, persistent zero C-operand.
__global__ __launch_bounds__(512, 4) void k_attn(
    const u16* __restrict__ qT, const u16* __restrict__ kT,
    const u16* __restrict__ v, u16* __restrict__ aoT) {
  __shared__ __align__(16) char lds[65536];    // 2 bufs x (K_A|K_B|V_A|V_B) x 8KB
  const int t = threadIdx.x, wv = t >> 6, ln = t & 63;
  const int l31 = ln & 31, hi = ln >> 5;
  const int qt = blockIdx.x, h = blockIdx.y, b = blockIdx.z;
  const size_t bh = (size_t)(b*8 + h);
  const int q0 = qt*256 + wv*32;
  const char* qp = (const char*)qT + (bh*1024 + q0)*128;
  const char* kp = (const char*)kT + bh*1024*128;
  const char* vp = (const char*)v  + bh*64*2048;

  const int srow = ln >> 3;
  const int csw16 = ((ln & 7) ^ srow) << 4;    // pre-swizzled source slot (bytes)
  const int rsw = (l31 & 7) << 4;              // read-side swizzle for this lane's rows
  const int grow = wv*8 + srow;                // this thread's staging row (0..63)

  auto stageChunk = [&](char* base, int mc) {  // one 128-key chunk (4 gload16/thread)
    gload16(base + wv*1024,         kp + (size_t)(mc*128 + grow)*128 + csw16);
    gload16(base + 8192 + wv*1024,  kp + (size_t)(mc*128 + 64 + grow)*128 + csw16);
    gload16(base + 16384 + wv*1024, vp + (size_t)grow*2048 + mc*256 + csw16);
    gload16(base + 24576 + wv*1024, vp + (size_t)grow*2048 + mc*256 + 128 + csw16);
  };

  // prologue: stage chunk 0 into buf 0
  stageChunk(lds, 0);

  bf16x8 qf[4];                                // Q B-frags: col=q(lane&31), k=d
  #pragma unroll
  for (int ks = 0; ks < 4; ks++)
    qf[ks] = *(const bf16x8*)(qp + (size_t)l31*128 + ks*32 + hi*16);

  f32x16 zv;                                   // persistent zero C-operand
  #pragma unroll
  for (int i = 0; i < 16; i++) zv[i] = 0.f;

  f32x16 o0, o1;                               // O^T accum
  #pragma unroll
  for (int i = 0; i < 16; i++) { o0[i] = 0.f; o1[i] = 0.f; }
  float M = -1e30f, L = 0.f;                   // L is own-half partial until epilogue

  // QK^T for one 64-key half (no accumulator init: first MFMA uses zv)
  auto qk = [&](const char* Kl, f32x16& s0, f32x16& s1) {
    __builtin_amdgcn_s_setprio(1);
    {
      int col = (hi*16) ^ rsw;
      bf16x8 k0 = *(const bf16x8*)(Kl + (size_t)l31*128 + col);
      bf16x8 k1 = *(const bf16x8*)(Kl + (size_t)(32 + l31)*128 + col);
      s0 = mfma32(k0, qf[0], zv);
      s1 = mfma32(k1, qf[0], zv);
    }
    #pragma unroll
    for (int ks = 1; ks < 4; ks++) {
      int col = (ks*32 + hi*16) ^ rsw;
      bf16x8 k0 = *(const bf16x8*)(Kl + (size_t)l31*128 + col);
      bf16x8 k1 = *(const bf16x8*)(Kl + (size_t)(32 + l31)*128 + col);
      s0 = mfma32(k0, qf[ks], s0);
      s1 = mfma32(k1, qf[ks], s1);
    }
    __builtin_amdgcn_s_setprio(0);
  };

  // softmax + P->bf16 frags for one half (updates M, L, rescales o on demand)
  auto sm = [&](f32x16& s0, f32x16& s1, bf16x8* pf) {
    float m8[8];
    #pragma unroll
    for (int i = 0; i < 8; i++)
      m8[i] = fmaxf(fmaxf(s0[2*i], s0[2*i+1]), fmaxf(s1[2*i], s1[2*i+1]));
    float m4a = fmaxf(m8[0], m8[1]), m4b = fmaxf(m8[2], m8[3]);
    float m4c = fmaxf(m8[4], m8[5]), m4d = fmaxf(m8[6], m8[7]);
    float cm = fmaxf(fmaxf(m4a, m4b), fmaxf(m4c, m4d));
    cm = fmaxf(cm, __shfl_xor(cm, 32));
    if (!__all(cm <= M + 11.f)) {              // defer-max: P bounded by 2^11
      float nm = fmaxf(M, cm);
      float al = exp2fast(M - nm);
      M = nm;
      #pragma unroll
      for (int i = 0; i < 16; i++) { o0[i] *= al; o1[i] *= al; }
      L *= al;
    }
    #pragma unroll
    for (int i = 0; i < 16; i++) {
      s0[i] = exp2fast(s0[i] - M);
      s1[i] = exp2fast(s1[i] - M);
    }
    float r8[8];
    #pragma unroll
    for (int i = 0; i < 8; i++)
      r8[i] = (s0[2*i] + s0[2*i+1]) + (s1[2*i] + s1[2*i+1]);
    float r4a = r8[0] + r8[1], r4b = r8[2] + r8[3];
    float r4c = r8[4] + r8[5], r4d = r8[6] + r8[7];
    L += (r4a + r4b) + (r4c + r4d);            // own-half partial only

    u32 x0 = cvtpk(s0[0],  s0[1]),  x1 = cvtpk(s0[2],  s0[3]);
    u32 x2 = cvtpk(s0[4],  s0[5]),  x3 = cvtpk(s0[6],  s0[7]);
    u32 x4 = cvtpk(s0[8],  s0[9]),  x5 = cvtpk(s0[10], s0[11]);
    u32 x6 = cvtpk(s0[12], s0[13]), x7 = cvtpk(s0[14], s0[15]);
    u32 y0 = cvtpk(s1[0],  s1[1]),  y1 = cvtpk(s1[2],  s1[3]);
    u32 y2 = cvtpk(s1[4],  s1[5]),  y3 = cvtpk(s1[6],  s1[7]);
    u32 y4 = cvtpk(s1[8],  s1[9]),  y5 = cvtpk(s1[10], s1[11]);
    u32 y6 = cvtpk(s1[12], s1[13]), y7 = cvtpk(s1[14], s1[15]);
    // packed one-direction exchange: each shfl carries what the OTHER half
    // needs (lo receives partner x0.., hi receives partner x2..).
    u32 e0 = (u32)__shfl_xor((int)(hi ? x0 : x2), 32);
    u32 e1 = (u32)__shfl_xor((int)(hi ? x1 : x3), 32);
    u32 e2 = (u32)__shfl_xor((int)(hi ? x4 : x6), 32);
    u32 e3 = (u32)__shfl_xor((int)(hi ? x5 : x7), 32);
    u32 f0 = (u32)__shfl_xor((int)(hi ? y0 : y2), 32);
    u32 f1 = (u32)__shfl_xor((int)(hi ? y1 : y3), 32);
    u32 f2 = (u32)__shfl_xor((int)(hi ? y4 : y6), 32);
    u32 f3 = (u32)__shfl_xor((int)(hi ? y5 : y7), 32);
    pf[0] = hi ? mkfrag(e0, e1, x2, x3) : mkfrag(x0, x1, e0, e1);
    pf[1] = hi ? mkfrag(e2, e3, x6, x7) : mkfrag(x4, x5, e2, e3);
    pf[2] = hi ? mkfrag(f0, f1, y2, y3) : mkfrag(y0, y1, f0, f1);
    pf[3] = hi ? mkfrag(f2, f3, y6, y7) : mkfrag(y4, y5, f2, f3);
  };

  auto pv = [&](const char* Vl, const bf16x8* pf) {
    __builtin_amdgcn_s_setprio(1);
    #pragma unroll
    for (int s = 0; s < 4; s++) {
      int col = (s*32 + hi*16) ^ rsw;
      bf16x8 v0 = *(const bf16x8*)(Vl + (size_t)l31*128 + col);
      bf16x8 v1 = *(const bf16x8*)(Vl + (size_t)(32 + l31)*128 + col);
      o0 = mfma32(v0, pf[s], o0);
      o1 = mfma32(v1, pf[s], o1);
    }
    __builtin_amdgcn_s_setprio(0);
  };

  __syncthreads();                             // chunk 0 staged (drains vmcnt)

  for (int mc = 0; mc < 8; mc++) {             // 8 rounds of 128 keys
    char* cb = lds + ((mc & 1) << 15);
    if (mc < 7) stageChunk(lds + (((mc + 1) & 1) << 15), mc + 1);
    f32x16 sa0, sa1, sb0, sb1;
    bf16x8 pfA[4], pfB[4];
    qk(cb, sa0, sa1);                          // QK_A
    sm(sa0, sa1, pfA);                         // SM_A
    qk(cb + 8192, sb0, sb1);                   // QK_B
    pv(cb + 16384, pfA);                       // PV_A
    sm(sb0, sb1, pfB);                         // SM_B
    pv(cb + 24576, pfB);                       // PV_B
    __syncthreads();                           // releases cur buf, publishes next buf
  }

  // ---- epilogue: merge cross-half L, then O/L -> aoT[b][n][c=h*64+d] bf16 ----
  L += __shfl_xor(L, 32);
  float inv = 1.f / L;
  u16* dst = aoT + ((size_t)(b*1024 + q0 + l31))*512 + h*64;
  #pragma unroll
  for (int qd = 0; qd < 4; qd++) {
    uint2 val;
    val.x = cvtpk(o0[4*qd+0]*inv, o0[4*qd+1]*inv);
    val.y = cvtpk(o0[4*qd+2]*inv, o0[4*qd+3]*inv);
    *(uint2*)(dst + qd*8 + hi*4) = val;
  }
  #pragma unroll
  for (int qd = 0; qd < 4; qd++) {
    uint2 val;
    val.x = cvtpk(o1[4*qd+0]*inv, o1[4*qd+1]*inv);
    val.y = cvtpk(o1[4*qd+2]*inv, o1[4*qd+3]*inv);
    *(uint2*)(dst + 32 + qd*8 + hi*4) = val;
  }
}

extern "C" void kernel_launch(void* const* d_in, const int* in_sizes, int n_in,
                              void* d_out, int out_size, void* d_ws, size_t ws_size,
                              hipStream_t stream) {
  const float* x     = (const float*)d_in[0];
  const float* nsc   = (const float*)d_in[1];
  const float* nbi   = (const float*)d_in[2];
  const float* qkvw  = (const float*)d_in[3];
  const float* qkvb  = (const float*)d_in[4];
  const float* projw = (const float*)d_in[5];
  const float* projb = (const float*)d_in[6];
  float* out = (float*)d_out;

  char* ws = (char*)d_ws;
  u16* qkvwb  = (u16*)(ws + 2048);                    // 1536*512*2
  u16* projwb = (u16*)(ws + 2048 + 1572864);          // 512*512*2
  char* p = ws + 2048 + 1572864 + 524288;
  u16* qT  = (u16*)p; p += 33554432;                  // [b][h][1024][64] bf16 (scaled)
  u16* kTb = (u16*)p; p += 33554432;                  // [b][h][1024][64] bf16
  u16* vb  = (u16*)p; p += 33554432;                  // [b][h][64][1024] bf16
  u16* xnT = (u16*)p;                                 // [b][1024][512] bf16, reused as aoT
  u16* aoT = xnT;

  k_cvt<<<768, 256, 0, stream>>>(qkvw, qkvwb, 1536*512);
  k_cvt<<<256, 256, 0, stream>>>(projw, projwb, 512*512);
  k_gn_norm_t<<<dim3(8, 32), 1024, 0, stream>>>(x, nsc, nbi, xnT);
  k_gemm<0><<<dim3(8, 12, 32), 256, 0, stream>>>(qkvwb, xnT, qkvb, nullptr,
                                                 qT, kTb, vb, nullptr);
  k_attn<<<dim3(4, 8, 32), 512, 0, stream>>>(qT, kTb, vb, aoT);
  k_gemm<1><<<dim3(8, 4, 32), 256, 0, stream>>>(projwb, aoT, projb, x,
                                                nullptr, nullptr, nullptr, out);
}

// Round 13
// 231.736 us; speedup vs baseline: 1.1123x; 1.0222x over previous
//
#include <hip/hip_runtime.h>
#include <stdint.h>

typedef float  f32x4  __attribute__((ext_vector_type(4)));
typedef float  f32x16 __attribute__((ext_vector_type(16)));
typedef __bf16 bf16x8 __attribute__((ext_vector_type(8)));
typedef unsigned int   u32;
typedef unsigned int   u32x4v __attribute__((ext_vector_type(4)));
typedef unsigned short u16;

#define DEVI static __device__ __forceinline__

DEVI void gload16(void* lds, const void* g) {
  __builtin_amdgcn_global_load_lds((const __attribute__((address_space(1))) u32*)g,
                                   (__attribute__((address_space(3))) u32*)lds, 16, 0, 0);
}
DEVI f32x4 mfma16(bf16x8 a, bf16x8 b, f32x4 c) {
  return __builtin_amdgcn_mfma_f32_16x16x32_bf16(a, b, c, 0, 0, 0);
}
DEVI f32x16 mfma32(bf16x8 a, bf16x8 b, f32x16 c) {
  return __builtin_amdgcn_mfma_f32_32x32x16_bf16(a, b, c, 0, 0, 0);
}
DEVI u16 f2bf(float f) {  // RNE f32->bf16 (finite inputs)
  u32 u = __builtin_bit_cast(u32, f);
  return (u16)((u + 0x7FFFu + ((u >> 16) & 1u)) >> 16);
}
DEVI u32 cvtpk(float lo, float hi) {  // packed f32->bf16 pair, lo in [15:0]
  u32 r;
  asm("v_cvt_pk_bf16_f32 %0, %1, %2" : "=v"(r) : "v"(lo), "v"(hi));
  return r;
}
DEVI bf16x8 mkfrag(u32 a, u32 b, u32 c, u32 d) {
  u32x4v u = {a, b, c, d};
  return __builtin_bit_cast(bf16x8, u);
}
#if __has_builtin(__builtin_amdgcn_exp2f)
DEVI float exp2fast(float x) { return __builtin_amdgcn_exp2f(x); }
#else
DEVI float exp2fast(float x) { return exp2f(x); }
#endif

// ---------------- fused GroupNorm stats + normalize + transpose.
// One block per (g,b): stats over the group's contiguous 64ch x 1024 f32
// (256 KB, HBM), then re-read (L2-hot) to normalize + transpose -> xnT bf16.
__global__ __launch_bounds__(1024) void k_gn_norm_t(
    const float* __restrict__ x, const float* __restrict__ scale,
    const float* __restrict__ bias, u16* __restrict__ xnT) {
  const int g = blockIdx.x, b = blockIdx.y;
  const float* xg = x + ((size_t)(b*8 + g)) * 65536;   // x[b][g*64..][0..1023]
  const int t = threadIdx.x;

  // ---- stats pass: 16384 float4, 1024 threads x 16 ----
  float s = 0.f, ss = 0.f;
  const float4* p4 = (const float4*)xg;
  #pragma unroll
  for (int i = 0; i < 16; i++) {
    float4 v = p4[t + i*1024];
    s  += v.x + v.y + v.z + v.w;
    ss += v.x*v.x + v.y*v.y + v.z*v.z + v.w*v.w;
  }
  #pragma unroll
  for (int off = 32; off; off >>= 1) { s += __shfl_down(s, off); ss += __shfl_down(ss, off); }
  __shared__ float sa[16], sb[16];
  __shared__ float stats[2];
  if ((t & 63) == 0) { sa[t >> 6] = s; sb[t >> 6] = ss; }
  __syncthreads();
  if (t == 0) {
    float S = 0.f, SS = 0.f;
    #pragma unroll
    for (int i = 0; i < 16; i++) { S += sa[i]; SS += sb[i]; }
    float mean = S * (1.f/65536.f);
    float var  = SS * (1.f/65536.f) - mean*mean;
    stats[0] = mean;
    stats[1] = rsqrtf(var + 1e-5f);
  }
  __syncthreads();
  const float mean = stats[0], rstd = stats[1];

  // ---- normalize + transpose: 16 n-tiles, 4 tiles in flight (4 x 256-thread groups)
  __shared__ __align__(16) char T[4][8192];    // [64 n][64 c] bf16, swizzled
  const int grp = t >> 8, lt = t & 255;
  const int n_l = lt & 63;
  for (int it = 0; it < 4; it++) {
    const int n0 = (it*4 + grp) * 64;
    #pragma unroll
    for (int i = 0; i < 16; i++) {
      int c_l = i*4 + (lt >> 6);
      float xv = xg[(size_t)c_l*1024 + n0 + n_l];  // L2-hot re-read
      float val = (xv - mean)*rstd*scale[g*64 + c_l] + bias[g*64 + c_l];
      *(u16*)(T[grp] + n_l*128 + ((c_l*2) ^ ((n_l&7)<<4))) = f2bf(val);
    }
    __syncthreads();
    u16* outp = xnT + ((size_t)b*1024 + n0)*512 + g*64;
    #pragma unroll
    for (int i = 0; i < 2; i++) {
      int idx = i*256 + lt;
      int n_ = idx >> 3, sl = idx & 7;
      uint4 val = *(const uint4*)(T[grp] + n_*128 + ((sl ^ (n_&7))<<4));
      *(uint4*)((char*)outp + (size_t)n_*1024 + sl*16) = val;
    }
    __syncthreads();
  }
}

// ---------------- f32 -> bf16 weight convert (both weight arrays, one launch)
__global__ __launch_bounds__(256) void k_cvt2(const float* __restrict__ a1,
                                              u16* __restrict__ o1, int n1,
                                              const float* __restrict__ a2,
                                              u16* __restrict__ o2, int n2) {
  int i = blockIdx.x * 256 + threadIdx.x;
  const int stride = gridDim.x * 256;
  for (; i < n1 + n2; i += stride) {
    if (i < n1) o1[i] = f2bf(a1[i]);
    else        o2[i - n1] = f2bf(a2[i - n1]);
  }
}

// ---------------- GEMM: C[128m x 128n] = A[M][512] * Bt[n][512]^T, per-batch B
// 2-phase LDS double-buffer: stage(t+1) issued before compute(t); 1 barrier/step.
// MODE 0: qkv -> q/k transposed [b][h][n][64] (q scaled 1/8*log2e), v natural [b][h][64][n]
// MODE 1: proj -> out = C + bias + residual (f32)
template<int MODE>
__global__ __launch_bounds__(256) void k_gemm(
    const u16* __restrict__ A, const u16* __restrict__ Bt,
    const float* __restrict__ bias, const float* __restrict__ xres,
    u16* __restrict__ oq, u16* __restrict__ ok, u16* __restrict__ ov,
    float* __restrict__ out) {
  __shared__ __align__(16) char lds[65536];   // 2 x (A 16K | B 16K); epilogue reuses 32K
  const int t = threadIdx.x;
  const int wv = t >> 6, ln = t & 63;
  const int wr = wv >> 1, wc = wv & 1;
  const int b  = blockIdx.z;
  const int n0 = blockIdx.x * 128;
  const int m0 = blockIdx.y * 128;
  const u16* Bb = Bt + (size_t)b * (1024*512);

  f32x4 acc[4][4];
  #pragma unroll
  for (int i = 0; i < 4; i++)
    #pragma unroll
    for (int j = 0; j < 4; j++) acc[i][j] = f32x4{0.f,0.f,0.f,0.f};

  const int srow = ln >> 3, ssl = ln & 7;
  const int csw  = ssl ^ (srow & 7);          // pre-swizzled source slot

  auto stage = [&](int buf, int kb) {
    char* base = lds + (buf << 15);
    #pragma unroll
    for (int i = 0; i < 4; i++) {
      int row = wv*32 + i*8 + srow;
      gload16(base + (wv*32 + i*8)*128,
              (const char*)A  + ((size_t)(m0+row)*512 + kb*64)*2 + csw*16);
      gload16(base + 16384 + (wv*32 + i*8)*128,
              (const char*)Bb + ((size_t)(n0+row)*512 + kb*64)*2 + csw*16);
    }
  };

  stage(0, 0);
  __syncthreads();                            // buf0 staged (drains vmcnt)

  for (int kb = 0; kb < 8; kb++) {            // K = 512, BK = 64
    if (kb < 7) stage((kb + 1) & 1, kb + 1);  // issue next tile into other buf
    const char* cb = lds + ((kb & 1) << 15);
    #pragma unroll
    for (int kf = 0; kf < 2; kf++) {
      bf16x8 af[4], bfr[4];
      #pragma unroll
      for (int mi = 0; mi < 4; mi++) {
        int row = wr*64 + mi*16 + (ln & 15);
        af[mi] = *(const bf16x8*)(cb + row*128 + ((kf*64 + ((ln>>4)<<4)) ^ ((row&7)<<4)));
      }
      #pragma unroll
      for (int ni = 0; ni < 4; ni++) {
        int row = wc*64 + ni*16 + (ln & 15);
        bfr[ni] = *(const bf16x8*)(cb + 16384 + row*128 + ((kf*64 + ((ln>>4)<<4)) ^ ((row&7)<<4)));
      }
      __builtin_amdgcn_s_setprio(1);
      #pragma unroll
      for (int mi = 0; mi < 4; mi++)
        #pragma unroll
        for (int ni = 0; ni < 4; ni++)
          acc[mi][ni] = mfma16(af[mi], bfr[ni], acc[mi][ni]);
      __builtin_amdgcn_s_setprio(0);
    }
    __syncthreads();                          // next buf staged; cur buf free
  }

  if constexpr (MODE == 0) {
    if (m0 >= 1024) {                          // V: natural [b][512=h*64+d][1024]
      #pragma unroll
      for (int mi = 0; mi < 4; mi++) {
        #pragma unroll
        for (int r = 0; r < 4; r++) {
          int o_l = wr*64 + mi*16 + ((ln>>4)<<2) + r;
          float bia = bias[m0 + o_l];
          size_t rowoff = ((size_t)b*512 + (m0-1024) + o_l)*1024 + n0 + wc*64 + (ln & 15);
          #pragma unroll
          for (int ni = 0; ni < 4; ni++)
            ov[rowoff + ni*16] = f2bf(acc[mi][ni][r] + bia);
        }
      }
    } else {                                   // Q/K: transpose via LDS -> [b][h][n][64]
      const bool isq = (m0 < 512);
      const float sq = isq ? 0.18033688f : 1.0f;  // d^-0.5 * log2(e) folded into q
      u16* dstb = isq ? oq : ok;
      const int mloc = isq ? m0 : (m0 - 512);
      #pragma unroll
      for (int mi = 0; mi < 4; mi++) {
        #pragma unroll
        for (int r = 0; r < 4; r++) {
          int o_l = wr*64 + mi*16 + ((ln>>4)<<2) + r;
          float bia = bias[m0 + o_l];
          #pragma unroll
          for (int ni = 0; ni < 4; ni++) {
            int n_l = wc*64 + ni*16 + (ln & 15);
            *(u16*)(lds + n_l*256 + ((o_l*2) ^ ((n_l&7)<<4))) =
                f2bf((acc[mi][ni][r] + bia) * sq);
          }
        }
      }
      __syncthreads();
      const int h0 = mloc >> 6;                // 2 heads per 128-row tile
      #pragma unroll
      for (int i = 0; i < 8; i++) {
        int idx = i*256 + t;
        int n_ = idx >> 4, s = idx & 15;
        uint4 val = *(const uint4*)(lds + n_*256 + ((s ^ (n_&7))<<4));
        u16* dst = dstb + ((size_t)(b*8 + h0 + (s>>3))*1024 + (n0 + n_))*64 + (s&7)*8;
        *(uint4*)dst = val;
      }
    }
  } else {                                     // proj: + bias + residual, f32 out
    #pragma unroll
    for (int mi = 0; mi < 4; mi++) {
      #pragma unroll
      for (int r = 0; r < 4; r++) {
        int o_l = wr*64 + mi*16 + ((ln>>4)<<2) + r;
        float bia = bias[m0 + o_l];
        size_t rowoff = ((size_t)b*512 + m0 + o_l)*1024 + n0 + wc*64 + (ln & 15);
        #pragma unroll
        for (int ni = 0; ni < 4; ni++)
          out[rowoff + ni*16] = acc[mi][ni][r] + bia + xres[rowoff + ni*16];
      }
    }
  }
}

// ---------------- flash attention (R10-proven body).
// R13: grid remapped to (bh=256, qt=4) so the 4 q-tile blocks sharing a
// (b,h) K/V stream land on the SAME XCD (linear-id%8 depends only on bh) —
// K/V chunks get L2-served instead of refetched per XCD. Loop-invariant LDS
// offsets hoisted.
__global__ __launch_bounds__(512, 4) void k_attn(
    const u16* __restrict__ qT, const u16* __restrict__ kT,
    const u16* __restrict__ v, u16* __restrict__ aoT) {
  __shared__ __align__(16) char lds[65536];    // 2 bufs x (K_A|K_B|V_A|V_B) x 8KB
  const int t = threadIdx.x, wv = t >> 6, ln = t & 63;
  const int l31 = ln & 31, hi = ln >> 5;
  const int bhi = blockIdx.x, qt = blockIdx.y;
  const int b = bhi >> 3, h = bhi & 7;
  const size_t bh = (size_t)(b*8 + h);
  const int q0 = qt*256 + wv*32;
  const char* qp = (const char*)qT + (bh*1024 + q0)*128;
  const char* kp = (const char*)kT + bh*1024*128;
  const char* vp = (const char*)v  + bh*64*2048;

  const int srow = ln >> 3;
  const int csw16 = ((ln & 7) ^ srow) << 4;    // pre-swizzled source slot (bytes)
  const int rsw = (l31 & 7) << 4;              // read-side swizzle for this lane's rows
  const int grow = wv*8 + srow;                // this thread's staging row (0..63)

  // loop-invariant LDS read offsets (bytes)
  const u32 rA = (u32)l31*128, rB = (u32)(32 + l31)*128;
  const u32 col0 = (u32)((0*32 + hi*16) ^ rsw);
  const u32 col1 = (u32)((1*32 + hi*16) ^ rsw);
  const u32 col2 = (u32)((2*32 + hi*16) ^ rsw);
  const u32 col3 = (u32)((3*32 + hi*16) ^ rsw);

  auto stageChunk = [&](char* base, int mc) {  // one 128-key chunk (4 gload16/thread)
    gload16(base + wv*1024,         kp + (size_t)(mc*128 + grow)*128 + csw16);
    gload16(base + 8192 + wv*1024,  kp + (size_t)(mc*128 + 64 + grow)*128 + csw16);
    gload16(base + 16384 + wv*1024, vp + (size_t)grow*2048 + mc*256 + csw16);
    gload16(base + 24576 + wv*1024, vp + (size_t)grow*2048 + mc*256 + 128 + csw16);
  };

  // prologue: stage chunk 0 into buf 0
  stageChunk(lds, 0);

  bf16x8 qf[4];                                // Q B-frags: col=q(lane&31), k=d
  #pragma unroll
  for (int ks = 0; ks < 4; ks++)
    qf[ks] = *(const bf16x8*)(qp + (size_t)l31*128 + ks*32 + hi*16);

  f32x16 zv;                                   // persistent zero C-operand
  #pragma unroll
  for (int i = 0; i < 16; i++) zv[i] = 0.f;

  f32x16 o0, o1;                               // O^T accum
  #pragma unroll
  for (int i = 0; i < 16; i++) { o0[i] = 0.f; o1[i] = 0.f; }
  float M = -1e30f, L = 0.f;                   // L is own-half partial until epilogue

  // QK^T for one 64-key half (no accumulator init: first MFMA uses zv)
  auto qk = [&](const char* Kl, f32x16& s0, f32x16& s1) {
    __builtin_amdgcn_s_setprio(1);
    {
      bf16x8 k0 = *(const bf16x8*)(Kl + rA + col0);
      bf16x8 k1 = *(const bf16x8*)(Kl + rB + col0);
      s0 = mfma32(k0, qf[0], zv);
      s1 = mfma32(k1, qf[0], zv);
    }
    {
      bf16x8 k0 = *(const bf16x8*)(Kl + rA + col1);
      bf16x8 k1 = *(const bf16x8*)(Kl + rB + col1);
      s0 = mfma32(k0, qf[1], s0);
      s1 = mfma32(k1, qf[1], s1);
    }
    {
      bf16x8 k0 = *(const bf16x8*)(Kl + rA + col2);
      bf16x8 k1 = *(const bf16x8*)(Kl + rB + col2);
      s0 = mfma32(k0, qf[2], s0);
      s1 = mfma32(k1, qf[2], s1);
    }
    {
      bf16x8 k0 = *(const bf16x8*)(Kl + rA + col3);
      bf16x8 k1 = *(const bf16x8*)(Kl + rB + col3);
      s0 = mfma32(k0, qf[3], s0);
      s1 = mfma32(k1, qf[3], s1);
    }
    __builtin_amdgcn_s_setprio(0);
  };

  // softmax + P->bf16 frags for one half (updates M, L, rescales o on demand)
  auto sm = [&](f32x16& s0, f32x16& s1, bf16x8* pf) {
    float m8[8];
    #pragma unroll
    for (int i = 0; i < 8; i++)
      m8[i] = fmaxf(fmaxf(s0[2*i], s0[2*i+1]), fmaxf(s1[2*i], s1[2*i+1]));
    float m4a = fmaxf(m8[0], m8[1]), m4b = fmaxf(m8[2], m8[3]);
    float m4c = fmaxf(m8[4], m8[5]), m4d = fmaxf(m8[6], m8[7]);
    float cm = fmaxf(fmaxf(m4a, m4b), fmaxf(m4c, m4d));
    cm = fmaxf(cm, __shfl_xor(cm, 32));
    if (!__all(cm <= M + 11.f)) {              // defer-max: P bounded by 2^11
      float nm = fmaxf(M, cm);
      float al = exp2fast(M - nm);
      M = nm;
      #pragma unroll
      for (int i = 0; i < 16; i++) { o0[i] *= al; o1[i] *= al; }
      L *= al;
    }
    #pragma unroll
    for (int i = 0; i < 16; i++) {
      s0[i] = exp2fast(s0[i] - M);
      s1[i] = exp2fast(s1[i] - M);
    }
    float r8[8];
    #pragma unroll
    for (int i = 0; i < 8; i++)
      r8[i] = (s0[2*i] + s0[2*i+1]) + (s1[2*i] + s1[2*i+1]);
    float r4a = r8[0] + r8[1], r4b = r8[2] + r8[3];
    float r4c = r8[4] + r8[5], r4d = r8[6] + r8[7];
    L += (r4a + r4b) + (r4c + r4d);            // own-half partial only

    u32 x0 = cvtpk(s0[0],  s0[1]),  x1 = cvtpk(s0[2],  s0[3]);
    u32 x2 = cvtpk(s0[4],  s0[5]),  x3 = cvtpk(s0[6],  s0[7]);
    u32 x4 = cvtpk(s0[8],  s0[9]),  x5 = cvtpk(s0[10], s0[11]);
    u32 x6 = cvtpk(s0[12], s0[13]), x7 = cvtpk(s0[14], s0[15]);
    u32 y0 = cvtpk(s1[0],  s1[1]),  y1 = cvtpk(s1[2],  s1[3]);
    u32 y2 = cvtpk(s1[4],  s1[5]),  y3 = cvtpk(s1[6],  s1[7]);
    u32 y4 = cvtpk(s1[8],  s1[9]),  y5 = cvtpk(s1[10], s1[11]);
    u32 y6 = cvtpk(s1[12], s1[13]), y7 = cvtpk(s1[14], s1[15]);
    // packed one-direction exchange: each shfl carries what the OTHER half
    // needs (lo receives partner x0.., hi receives partner x2..).
    u32 e0 = (u32)__shfl_xor((int)(hi ? x0 : x2), 32);
    u32 e1 = (u32)__shfl_xor((int)(hi ? x1 : x3), 32);
    u32 e2 = (u32)__shfl_xor((int)(hi ? x4 : x6), 32);
    u32 e3 = (u32)__shfl_xor((int)(hi ? x5 : x7), 32);
    u32 f0 = (u32)__shfl_xor((int)(hi ? y0 : y2), 32);
    u32 f1 = (u32)__shfl_xor((int)(hi ? y1 : y3), 32);
    u32 f2 = (u32)__shfl_xor((int)(hi ? y4 : y6), 32);
    u32 f3 = (u32)__shfl_xor((int)(hi ? y5 : y7), 32);
    pf[0] = hi ? mkfrag(e0, e1, x2, x3) : mkfrag(x0, x1, e0, e1);
    pf[1] = hi ? mkfrag(e2, e3, x6, x7) : mkfrag(x4, x5, e2, e3);
    pf[2] = hi ? mkfrag(f0, f1, y2, y3) : mkfrag(y0, y1, f0, f1);
    pf[3] = hi ? mkfrag(f2, f3, y6, y7) : mkfrag(y4, y5, f2, f3);
  };

  auto pv = [&](const char* Vl, const bf16x8* pf) {
    __builtin_amdgcn_s_setprio(1);
    {
      bf16x8 v0 = *(const bf16x8*)(Vl + rA + col0);
      bf16x8 v1 = *(const bf16x8*)(Vl + rB + col0);
      o0 = mfma32(v0, pf[0], o0);
      o1 = mfma32(v1, pf[0], o1);
    }
    {
      bf16x8 v0 = *(const bf16x8*)(Vl + rA + col1);
      bf16x8 v1 = *(const bf16x8*)(Vl + rB + col1);
      o0 = mfma32(v0, pf[1], o0);
      o1 = mfma32(v1, pf[1], o1);
    }
    {
      bf16x8 v0 = *(const bf16x8*)(Vl + rA + col2);
      bf16x8 v1 = *(const bf16x8*)(Vl + rB + col2);
      o0 = mfma32(v0, pf[2], o0);
      o1 = mfma32(v1, pf[2], o1);
    }
    {
      bf16x8 v0 = *(const bf16x8*)(Vl + rA + col3);
      bf16x8 v1 = *(const bf16x8*)(Vl + rB + col3);
      o0 = mfma32(v0, pf[3], o0);
      o1 = mfma32(v1, pf[3], o1);
    }
    __builtin_amdgcn_s_setprio(0);
  };

  __syncthreads();                             // chunk 0 staged (drains vmcnt)

  for (int mc = 0; mc < 8; mc++) {             // 8 rounds of 128 keys
    char* cb = lds + ((mc & 1) << 15);
    if (mc < 7) stageChunk(lds + (((mc + 1) & 1) << 15), mc + 1);
    f32x16 sa0, sa1, sb0, sb1;
    bf16x8 pfA[4], pfB[4];
    qk(cb, sa0, sa1);                          // QK_A
    sm(sa0, sa1, pfA);                         // SM_A
    qk(cb + 8192, sb0, sb1);                   // QK_B
    pv(cb + 16384, pfA);                       // PV_A
    sm(sb0, sb1, pfB);                         // SM_B
    pv(cb + 24576, pfB);                       // PV_B
    __syncthreads();                           // releases cur buf, publishes next buf
  }

  // ---- epilogue: merge cross-half L, then O/L -> aoT[b][n][c=h*64+d] bf16 ----
  L += __shfl_xor(L, 32);
  float inv = 1.f / L;
  u16* dst = aoT + ((size_t)(b*1024 + q0 + l31))*512 + h*64;
  #pragma unroll
  for (int qd = 0; qd < 4; qd++) {
    uint2 val;
    val.x = cvtpk(o0[4*qd+0]*inv, o0[4*qd+1]*inv);
    val.y = cvtpk(o0[4*qd+2]*inv, o0[4*qd+3]*inv);
    *(uint2*)(dst + qd*8 + hi*4) = val;
  }
  #pragma unroll
  for (int qd = 0; qd < 4; qd++) {
    uint2 val;
    val.x = cvtpk(o1[4*qd+0]*inv, o1[4*qd+1]*inv);
    val.y = cvtpk(o1[4*qd+2]*inv, o1[4*qd+3]*inv);
    *(uint2*)(dst + 32 + qd*8 + hi*4) = val;
  }
}

extern "C" void kernel_launch(void* const* d_in, const int* in_sizes, int n_in,
                              void* d_out, int out_size, void* d_ws, size_t ws_size,
                              hipStream_t stream) {
  const float* x     = (const float*)d_in[0];
  const float* nsc   = (const float*)d_in[1];
  const float* nbi   = (const float*)d_in[2];
  const float* qkvw  = (const float*)d_in[3];
  const float* qkvb  = (const float*)d_in[4];
  const float* projw = (const float*)d_in[5];
  const float* projb = (const float*)d_in[6];
  float* out = (float*)d_out;

  char* ws = (char*)d_ws;
  u16* qkvwb  = (u16*)(ws + 2048);                    // 1536*512*2
  u16* projwb = (u16*)(ws + 2048 + 1572864);          // 512*512*2
  char* p = ws + 2048 + 1572864 + 524288;
  u16* qT  = (u16*)p; p += 33554432;                  // [b][h][1024][64] bf16 (scaled)
  u16* kTb = (u16*)p; p += 33554432;                  // [b][h][1024][64] bf16
  u16* vb  = (u16*)p; p += 33554432;                  // [b][h][64][1024] bf16
  u16* xnT = (u16*)p;                                 // [b][1024][512] bf16, reused as aoT
  u16* aoT = xnT;

  k_cvt2<<<1024, 256, 0, stream>>>(qkvw, qkvwb, 1536*512, projw, projwb, 512*512);
  k_gn_norm_t<<<dim3(8, 32), 1024, 0, stream>>>(x, nsc, nbi, xnT);
  k_gemm<0><<<dim3(8, 12, 32), 256, 0, stream>>>(qkvwb, xnT, qkvb, nullptr,
                                                 qT, kTb, vb, nullptr);
  k_attn<<<dim3(256, 4), 512, 0, stream>>>(qT, kTb, vb, aoT);
  k_gemm<1><<<dim3(8, 4, 32), 256, 0, stream>>>(projwb, aoT, projb, x,
                                                nullptr, nullptr, nullptr, out);
}

// Round 14
// 229.452 us; speedup vs baseline: 1.1234x; 1.0100x over previous
//
#include <hip/hip_runtime.h>
#include <stdint.h>

typedef float  f32x4  __attribute__((ext_vector_type(4)));
typedef float  f32x16 __attribute__((ext_vector_type(16)));
typedef __bf16 bf16x8 __attribute__((ext_vector_type(8)));
typedef unsigned int   u32;
typedef unsigned int   u32x4v __attribute__((ext_vector_type(4)));
typedef unsigned short u16;

#define DEVI static __device__ __forceinline__

DEVI void gload16(void* lds, const void* g) {
  __builtin_amdgcn_global_load_lds((const __attribute__((address_space(1))) u32*)g,
                                   (__attribute__((address_space(3))) u32*)lds, 16, 0, 0);
}
DEVI f32x4 mfma16(bf16x8 a, bf16x8 b, f32x4 c) {
  return __builtin_amdgcn_mfma_f32_16x16x32_bf16(a, b, c, 0, 0, 0);
}
DEVI f32x16 mfma32(bf16x8 a, bf16x8 b, f32x16 c) {
  return __builtin_amdgcn_mfma_f32_32x32x16_bf16(a, b, c, 0, 0, 0);
}
DEVI u16 f2bf(float f) {  // RNE f32->bf16 (finite inputs)
  u32 u = __builtin_bit_cast(u32, f);
  return (u16)((u + 0x7FFFu + ((u >> 16) & 1u)) >> 16);
}
DEVI u32 cvtpk(float lo, float hi) {  // packed f32->bf16 pair, lo in [15:0]
  u32 r;
  asm("v_cvt_pk_bf16_f32 %0, %1, %2" : "=v"(r) : "v"(lo), "v"(hi));
  return r;
}
DEVI bf16x8 mkfrag(u32 a, u32 b, u32 c, u32 d) {
  u32x4v u = {a, b, c, d};
  return __builtin_bit_cast(bf16x8, u);
}
#if __has_builtin(__builtin_amdgcn_exp2f)
DEVI float exp2fast(float x) { return __builtin_amdgcn_exp2f(x); }
#else
DEVI float exp2fast(float x) { return exp2f(x); }
#endif

// ---------------- fused weight-cvt + GroupNorm stats + normalize + transpose.
// One block per (g,b). Extra duty: each thread converts 4 f32 weights -> bf16
// (removes the standalone cvt launch from the serial chain; hides under the
// stats pass' HBM latency). Then stats over the group's contiguous 64ch x
// 1024 f32, then L2-hot re-read to normalize + transpose -> xnT bf16.
__global__ __launch_bounds__(1024) void k_gn_norm_t(
    const float* __restrict__ x, const float* __restrict__ scale,
    const float* __restrict__ bias, u16* __restrict__ xnT,
    const float* __restrict__ qkvw, u16* __restrict__ qkvwb,
    const float* __restrict__ projw, u16* __restrict__ projwb) {
  const int g = blockIdx.x, b = blockIdx.y;
  const float* xg = x + ((size_t)(b*8 + g)) * 65536;   // x[b][g*64..][0..1023]
  const int t = threadIdx.x;

  // ---- weight conversion slice: 1,048,576 elems = 262,144 float4 groups ----
  {
    int gi = (b*8 + g)*1024 + t;                       // 0..262143
    float4 w = (gi < 196608) ? ((const float4*)qkvw)[gi]
                             : ((const float4*)projw)[gi - 196608];
    ushort4 pk = { f2bf(w.x), f2bf(w.y), f2bf(w.z), f2bf(w.w) };
    if (gi < 196608) ((ushort4*)qkvwb)[gi] = pk;
    else             ((ushort4*)projwb)[gi - 196608] = pk;
  }

  // ---- stats pass: 16384 float4, 1024 threads x 16 ----
  float s = 0.f, ss = 0.f;
  const float4* p4 = (const float4*)xg;
  #pragma unroll
  for (int i = 0; i < 16; i++) {
    float4 v = p4[t + i*1024];
    s  += v.x + v.y + v.z + v.w;
    ss += v.x*v.x + v.y*v.y + v.z*v.z + v.w*v.w;
  }
  #pragma unroll
  for (int off = 32; off; off >>= 1) { s += __shfl_down(s, off); ss += __shfl_down(ss, off); }
  __shared__ float sa[16], sb[16];
  __shared__ float stats[2];
  if ((t & 63) == 0) { sa[t >> 6] = s; sb[t >> 6] = ss; }
  __syncthreads();
  if (t == 0) {
    float S = 0.f, SS = 0.f;
    #pragma unroll
    for (int i = 0; i < 16; i++) { S += sa[i]; SS += sb[i]; }
    float mean = S * (1.f/65536.f);
    float var  = SS * (1.f/65536.f) - mean*mean;
    stats[0] = mean;
    stats[1] = rsqrtf(var + 1e-5f);
  }
  __syncthreads();
  const float mean = stats[0], rstd = stats[1];

  // ---- normalize + transpose: 16 n-tiles, 4 tiles in flight (4 x 256-thread groups)
  __shared__ __align__(16) char T[4][8192];    // [64 n][64 c] bf16, swizzled
  const int grp = t >> 8, lt = t & 255;
  const int n_l = lt & 63;
  for (int it = 0; it < 4; it++) {
    const int n0 = (it*4 + grp) * 64;
    #pragma unroll
    for (int i = 0; i < 16; i++) {
      int c_l = i*4 + (lt >> 6);
      float xv = xg[(size_t)c_l*1024 + n0 + n_l];  // L2-hot re-read
      float val = (xv - mean)*rstd*scale[g*64 + c_l] + bias[g*64 + c_l];
      *(u16*)(T[grp] + n_l*128 + ((c_l*2) ^ ((n_l&7)<<4))) = f2bf(val);
    }
    __syncthreads();
    u16* outp = xnT + ((size_t)b*1024 + n0)*512 + g*64;
    #pragma unroll
    for (int i = 0; i < 2; i++) {
      int idx = i*256 + lt;
      int n_ = idx >> 3, sl = idx & 7;
      uint4 val = *(const uint4*)(T[grp] + n_*128 + ((sl ^ (n_&7))<<4));
      *(uint4*)((char*)outp + (size_t)n_*1024 + sl*16) = val;
    }
    __syncthreads();
  }
}

// ---------------- GEMM: C[128m x 128n] = A[M][512] * Bt[n][512]^T, per-batch B
// 2-phase LDS double-buffer: stage(t+1) issued before compute(t); 1 barrier/step.
// MODE 0: qkv -> q/k transposed [b][h][n][64] (q scaled 1/8*log2e), v natural [b][h][64][n]
// MODE 1: proj -> out = C + bias + residual (f32)
template<int MODE>
__global__ __launch_bounds__(256) void k_gemm(
    const u16* __restrict__ A, const u16* __restrict__ Bt,
    const float* __restrict__ bias, const float* __restrict__ xres,
    u16* __restrict__ oq, u16* __restrict__ ok, u16* __restrict__ ov,
    float* __restrict__ out) {
  __shared__ __align__(16) char lds[65536];   // 2 x (A 16K | B 16K); epilogue reuses 32K
  const int t = threadIdx.x;
  const int wv = t >> 6, ln = t & 63;
  const int wr = wv >> 1, wc = wv & 1;
  const int b  = blockIdx.z;
  const int n0 = blockIdx.x * 128;
  const int m0 = blockIdx.y * 128;
  const u16* Bb = Bt + (size_t)b * (1024*512);

  f32x4 acc[4][4];
  #pragma unroll
  for (int i = 0; i < 4; i++)
    #pragma unroll
    for (int j = 0; j < 4; j++) acc[i][j] = f32x4{0.f,0.f,0.f,0.f};

  const int srow = ln >> 3, ssl = ln & 7;
  const int csw  = ssl ^ (srow & 7);          // pre-swizzled source slot

  auto stage = [&](int buf, int kb) {
    char* base = lds + (buf << 15);
    #pragma unroll
    for (int i = 0; i < 4; i++) {
      int row = wv*32 + i*8 + srow;
      gload16(base + (wv*32 + i*8)*128,
              (const char*)A  + ((size_t)(m0+row)*512 + kb*64)*2 + csw*16);
      gload16(base + 16384 + (wv*32 + i*8)*128,
              (const char*)Bb + ((size_t)(n0+row)*512 + kb*64)*2 + csw*16);
    }
  };

  stage(0, 0);
  __syncthreads();                            // buf0 staged (drains vmcnt)

  for (int kb = 0; kb < 8; kb++) {            // K = 512, BK = 64
    if (kb < 7) stage((kb + 1) & 1, kb + 1);  // issue next tile into other buf
    const char* cb = lds + ((kb & 1) << 15);
    #pragma unroll
    for (int kf = 0; kf < 2; kf++) {
      bf16x8 af[4], bfr[4];
      #pragma unroll
      for (int mi = 0; mi < 4; mi++) {
        int row = wr*64 + mi*16 + (ln & 15);
        af[mi] = *(const bf16x8*)(cb + row*128 + ((kf*64 + ((ln>>4)<<4)) ^ ((row&7)<<4)));
      }
      #pragma unroll
      for (int ni = 0; ni < 4; ni++) {
        int row = wc*64 + ni*16 + (ln & 15);
        bfr[ni] = *(const bf16x8*)(cb + 16384 + row*128 + ((kf*64 + ((ln>>4)<<4)) ^ ((row&7)<<4)));
      }
      __builtin_amdgcn_s_setprio(1);
      #pragma unroll
      for (int mi = 0; mi < 4; mi++)
        #pragma unroll
        for (int ni = 0; ni < 4; ni++)
          acc[mi][ni] = mfma16(af[mi], bfr[ni], acc[mi][ni]);
      __builtin_amdgcn_s_setprio(0);
    }
    __syncthreads();                          // next buf staged; cur buf free
  }

  if constexpr (MODE == 0) {
    if (m0 >= 1024) {                          // V: natural [b][512=h*64+d][1024]
      #pragma unroll
      for (int mi = 0; mi < 4; mi++) {
        #pragma unroll
        for (int r = 0; r < 4; r++) {
          int o_l = wr*64 + mi*16 + ((ln>>4)<<2) + r;
          float bia = bias[m0 + o_l];
          size_t rowoff = ((size_t)b*512 + (m0-1024) + o_l)*1024 + n0 + wc*64 + (ln & 15);
          #pragma unroll
          for (int ni = 0; ni < 4; ni++)
            ov[rowoff + ni*16] = f2bf(acc[mi][ni][r] + bia);
        }
      }
    } else {                                   // Q/K: transpose via LDS -> [b][h][n][64]
      const bool isq = (m0 < 512);
      const float sq = isq ? 0.18033688f : 1.0f;  // d^-0.5 * log2(e) folded into q
      u16* dstb = isq ? oq : ok;
      const int mloc = isq ? m0 : (m0 - 512);
      #pragma unroll
      for (int mi = 0; mi < 4; mi++) {
        #pragma unroll
        for (int r = 0; r < 4; r++) {
          int o_l = wr*64 + mi*16 + ((ln>>4)<<2) + r;
          float bia = bias[m0 + o_l];
          #pragma unroll
          for (int ni = 0; ni < 4; ni++) {
            int n_l = wc*64 + ni*16 + (ln & 15);
            *(u16*)(lds + n_l*256 + ((o_l*2) ^ ((n_l&7)<<4))) =
                f2bf((acc[mi][ni][r] + bia) * sq);
          }
        }
      }
      __syncthreads();
      const int h0 = mloc >> 6;                // 2 heads per 128-row tile
      #pragma unroll
      for (int i = 0; i < 8; i++) {
        int idx = i*256 + t;
        int n_ = idx >> 4, s = idx & 15;
        uint4 val = *(const uint4*)(lds + n_*256 + ((s ^ (n_&7))<<4));
        u16* dst = dstb + ((size_t)(b*8 + h0 + (s>>3))*1024 + (n0 + n_))*64 + (s&7)*8;
        *(uint4*)dst = val;
      }
    }
  } else {                                     // proj: + bias + residual, f32 out
    #pragma unroll
    for (int mi = 0; mi < 4; mi++) {
      #pragma unroll
      for (int r = 0; r < 4; r++) {
        int o_l = wr*64 + mi*16 + ((ln>>4)<<2) + r;
        float bia = bias[m0 + o_l];
        size_t rowoff = ((size_t)b*512 + m0 + o_l)*1024 + n0 + wc*64 + (ln & 15);
        #pragma unroll
        for (int ni = 0; ni < 4; ni++)
          out[rowoff + ni*16] = acc[mi][ni][r] + bia + xres[rowoff + ni*16];
      }
    }
  }
}

// ---------------- flash attention (R10-proven body; R13 grid (bh, qt)).
__global__ __launch_bounds__(512, 4) void k_attn(
    const u16* __restrict__ qT, const u16* __restrict__ kT,
    const u16* __restrict__ v, u16* __restrict__ aoT) {
  __shared__ __align__(16) char lds[65536];    // 2 bufs x (K_A|K_B|V_A|V_B) x 8KB
  const int t = threadIdx.x, wv = t >> 6, ln = t & 63;
  const int l31 = ln & 31, hi = ln >> 5;
  const int bhi = blockIdx.x, qt = blockIdx.y;
  const int b = bhi >> 3, h = bhi & 7;
  const size_t bh = (size_t)(b*8 + h);
  const int q0 = qt*256 + wv*32;
  const char* qp = (const char*)qT + (bh*1024 + q0)*128;
  const char* kp = (const char*)kT + bh*1024*128;
  const char* vp = (const char*)v  + bh*64*2048;

  const int srow = ln >> 3;
  const int csw16 = ((ln & 7) ^ srow) << 4;    // pre-swizzled source slot (bytes)
  const int rsw = (l31 & 7) << 4;              // read-side swizzle for this lane's rows
  const int grow = wv*8 + srow;                // this thread's staging row (0..63)

  // loop-invariant LDS read offsets (bytes)
  const u32 rA = (u32)l31*128, rB = (u32)(32 + l31)*128;
  const u32 col0 = (u32)((0*32 + hi*16) ^ rsw);
  const u32 col1 = (u32)((1*32 + hi*16) ^ rsw);
  const u32 col2 = (u32)((2*32 + hi*16) ^ rsw);
  const u32 col3 = (u32)((3*32 + hi*16) ^ rsw);

  auto stageChunk = [&](char* base, int mc) {  // one 128-key chunk (4 gload16/thread)
    gload16(base + wv*1024,         kp + (size_t)(mc*128 + grow)*128 + csw16);
    gload16(base + 8192 + wv*1024,  kp + (size_t)(mc*128 + 64 + grow)*128 + csw16);
    gload16(base + 16384 + wv*1024, vp + (size_t)grow*2048 + mc*256 + csw16);
    gload16(base + 24576 + wv*1024, vp + (size_t)grow*2048 + mc*256 + 128 + csw16);
  };

  // prologue: stage chunk 0 into buf 0
  stageChunk(lds, 0);

  bf16x8 qf[4];                                // Q B-frags: col=q(lane&31), k=d
  #pragma unroll
  for (int ks = 0; ks < 4; ks++)
    qf[ks] = *(const bf16x8*)(qp + (size_t)l31*128 + ks*32 + hi*16);

  f32x16 zv;                                   // persistent zero C-operand
  #pragma unroll
  for (int i = 0; i < 16; i++) zv[i] = 0.f;

  f32x16 o0, o1;                               // O^T accum
  #pragma unroll
  for (int i = 0; i < 16; i++) { o0[i] = 0.f; o1[i] = 0.f; }
  float M = -1e30f, L = 0.f;                   // L is own-half partial until epilogue

  // QK^T for one 64-key half (no accumulator init: first MFMA uses zv)
  auto qk = [&](const char* Kl, f32x16& s0, f32x16& s1) {
    __builtin_amdgcn_s_setprio(1);
    {
      bf16x8 k0 = *(const bf16x8*)(Kl + rA + col0);
      bf16x8 k1 = *(const bf16x8*)(Kl + rB + col0);
      s0 = mfma32(k0, qf[0], zv);
      s1 = mfma32(k1, qf[0], zv);
    }
    {
      bf16x8 k0 = *(const bf16x8*)(Kl + rA + col1);
      bf16x8 k1 = *(const bf16x8*)(Kl + rB + col1);
      s0 = mfma32(k0, qf[1], s0);
      s1 = mfma32(k1, qf[1], s1);
    }
    {
      bf16x8 k0 = *(const bf16x8*)(Kl + rA + col2);
      bf16x8 k1 = *(const bf16x8*)(Kl + rB + col2);
      s0 = mfma32(k0, qf[2], s0);
      s1 = mfma32(k1, qf[2], s1);
    }
    {
      bf16x8 k0 = *(const bf16x8*)(Kl + rA + col3);
      bf16x8 k1 = *(const bf16x8*)(Kl + rB + col3);
      s0 = mfma32(k0, qf[3], s0);
      s1 = mfma32(k1, qf[3], s1);
    }
    __builtin_amdgcn_s_setprio(0);
  };

  // softmax + P->bf16 frags for one half (updates M, L, rescales o on demand)
  auto sm = [&](f32x16& s0, f32x16& s1, bf16x8* pf) {
    float m8[8];
    #pragma unroll
    for (int i = 0; i < 8; i++)
      m8[i] = fmaxf(fmaxf(s0[2*i], s0[2*i+1]), fmaxf(s1[2*i], s1[2*i+1]));
    float m4a = fmaxf(m8[0], m8[1]), m4b = fmaxf(m8[2], m8[3]);
    float m4c = fmaxf(m8[4], m8[5]), m4d = fmaxf(m8[6], m8[7]);
    float cm = fmaxf(fmaxf(m4a, m4b), fmaxf(m4c, m4d));
    cm = fmaxf(cm, __shfl_xor(cm, 32));
    if (!__all(cm <= M + 11.f)) {              // defer-max: P bounded by 2^11
      float nm = fmaxf(M, cm);
      float al = exp2fast(M - nm);
      M = nm;
      #pragma unroll
      for (int i = 0; i < 16; i++) { o0[i] *= al; o1[i] *= al; }
      L *= al;
    }
    #pragma unroll
    for (int i = 0; i < 16; i++) {
      s0[i] = exp2fast(s0[i] - M);
      s1[i] = exp2fast(s1[i] - M);
    }
    float r8[8];
    #pragma unroll
    for (int i = 0; i < 8; i++)
      r8[i] = (s0[2*i] + s0[2*i+1]) + (s1[2*i] + s1[2*i+1]);
    float r4a = r8[0] + r8[1], r4b = r8[2] + r8[3];
    float r4c = r8[4] + r8[5], r4d = r8[6] + r8[7];
    L += (r4a + r4b) + (r4c + r4d);            // own-half partial only

    u32 x0 = cvtpk(s0[0],  s0[1]),  x1 = cvtpk(s0[2],  s0[3]);
    u32 x2 = cvtpk(s0[4],  s0[5]),  x3 = cvtpk(s0[6],  s0[7]);
    u32 x4 = cvtpk(s0[8],  s0[9]),  x5 = cvtpk(s0[10], s0[11]);
    u32 x6 = cvtpk(s0[12], s0[13]), x7 = cvtpk(s0[14], s0[15]);
    u32 y0 = cvtpk(s1[0],  s1[1]),  y1 = cvtpk(s1[2],  s1[3]);
    u32 y2 = cvtpk(s1[4],  s1[5]),  y3 = cvtpk(s1[6],  s1[7]);
    u32 y4 = cvtpk(s1[8],  s1[9]),  y5 = cvtpk(s1[10], s1[11]);
    u32 y6 = cvtpk(s1[12], s1[13]), y7 = cvtpk(s1[14], s1[15]);
    // packed one-direction exchange: each shfl carries what the OTHER half
    // needs (lo receives partner x0.., hi receives partner x2..).
    u32 e0 = (u32)__shfl_xor((int)(hi ? x0 : x2), 32);
    u32 e1 = (u32)__shfl_xor((int)(hi ? x1 : x3), 32);
    u32 e2 = (u32)__shfl_xor((int)(hi ? x4 : x6), 32);
    u32 e3 = (u32)__shfl_xor((int)(hi ? x5 : x7), 32);
    u32 f0 = (u32)__shfl_xor((int)(hi ? y0 : y2), 32);
    u32 f1 = (u32)__shfl_xor((int)(hi ? y1 : y3), 32);
    u32 f2 = (u32)__shfl_xor((int)(hi ? y4 : y6), 32);
    u32 f3 = (u32)__shfl_xor((int)(hi ? y5 : y7), 32);
    pf[0] = hi ? mkfrag(e0, e1, x2, x3) : mkfrag(x0, x1, e0, e1);
    pf[1] = hi ? mkfrag(e2, e3, x6, x7) : mkfrag(x4, x5, e2, e3);
    pf[2] = hi ? mkfrag(f0, f1, y2, y3) : mkfrag(y0, y1, f0, f1);
    pf[3] = hi ? mkfrag(f2, f3, y6, y7) : mkfrag(y4, y5, f2, f3);
  };

  auto pv = [&](const char* Vl, const bf16x8* pf) {
    __builtin_amdgcn_s_setprio(1);
    {
      bf16x8 v0 = *(const bf16x8*)(Vl + rA + col0);
      bf16x8 v1 = *(const bf16x8*)(Vl + rB + col0);
      o0 = mfma32(v0, pf[0], o0);
      o1 = mfma32(v1, pf[0], o1);
    }
    {
      bf16x8 v0 = *(const bf16x8*)(Vl + rA + col1);
      bf16x8 v1 = *(const bf16x8*)(Vl + rB + col1);
      o0 = mfma32(v0, pf[1], o0);
      o1 = mfma32(v1, pf[1], o1);
    }
    {
      bf16x8 v0 = *(const bf16x8*)(Vl + rA + col2);
      bf16x8 v1 = *(const bf16x8*)(Vl + rB + col2);
      o0 = mfma32(v0, pf[2], o0);
      o1 = mfma32(v1, pf[2], o1);
    }
    {
      bf16x8 v0 = *(const bf16x8*)(Vl + rA + col3);
      bf16x8 v1 = *(const bf16x8*)(Vl + rB + col3);
      o0 = mfma32(v0, pf[3], o0);
      o1 = mfma32(v1, pf[3], o1);
    }
    __builtin_amdgcn_s_setprio(0);
  };

  __syncthreads();                             // chunk 0 staged (drains vmcnt)

  for (int mc = 0; mc < 8; mc++) {             // 8 rounds of 128 keys
    char* cb = lds + ((mc & 1) << 15);
    if (mc < 7) stageChunk(lds + (((mc + 1) & 1) << 15), mc + 1);
    f32x16 sa0, sa1, sb0, sb1;
    bf16x8 pfA[4], pfB[4];
    qk(cb, sa0, sa1);                          // QK_A
    sm(sa0, sa1, pfA);                         // SM_A
    qk(cb + 8192, sb0, sb1);                   // QK_B
    pv(cb + 16384, pfA);                       // PV_A
    sm(sb0, sb1, pfB);                         // SM_B
    pv(cb + 24576, pfB);                       // PV_B
    __syncthreads();                           // releases cur buf, publishes next buf
  }

  // ---- epilogue: merge cross-half L, then O/L -> aoT[b][n][c=h*64+d] bf16 ----
  L += __shfl_xor(L, 32);
  float inv = 1.f / L;
  u16* dst = aoT + ((size_t)(b*1024 + q0 + l31))*512 + h*64;
  #pragma unroll
  for (int qd = 0; qd < 4; qd++) {
    uint2 val;
    val.x = cvtpk(o0[4*qd+0]*inv, o0[4*qd+1]*inv);
    val.y = cvtpk(o0[4*qd+2]*inv, o0[4*qd+3]*inv);
    *(uint2*)(dst + qd*8 + hi*4) = val;
  }
  #pragma unroll
  for (int qd = 0; qd < 4; qd++) {
    uint2 val;
    val.x = cvtpk(o1[4*qd+0]*inv, o1[4*qd+1]*inv);
    val.y = cvtpk(o1[4*qd+2]*inv, o1[4*qd+3]*inv);
    *(uint2*)(dst + 32 + qd*8 + hi*4) = val;
  }
}

extern "C" void kernel_launch(void* const* d_in, const int* in_sizes, int n_in,
                              void* d_out, int out_size, void* d_ws, size_t ws_size,
                              hipStream_t stream) {
  const float* x     = (const float*)d_in[0];
  const float* nsc   = (const float*)d_in[1];
  const float* nbi   = (const float*)d_in[2];
  const float* qkvw  = (const float*)d_in[3];
  const float* qkvb  = (const float*)d_in[4];
  const float* projw = (const float*)d_in[5];
  const float* projb = (const float*)d_in[6];
  float* out = (float*)d_out;

  char* ws = (char*)d_ws;
  u16* qkvwb  = (u16*)(ws + 2048);                    // 1536*512*2
  u16* projwb = (u16*)(ws + 2048 + 1572864);          // 512*512*2
  char* p = ws + 2048 + 1572864 + 524288;
  u16* qT  = (u16*)p; p += 33554432;                  // [b][h][1024][64] bf16 (scaled)
  u16* kTb = (u16*)p; p += 33554432;                  // [b][h][1024][64] bf16
  u16* vb  = (u16*)p; p += 33554432;                  // [b][h][64][1024] bf16
  u16* xnT = (u16*)p;                                 // [b][1024][512] bf16, reused as aoT
  u16* aoT = xnT;

  k_gn_norm_t<<<dim3(8, 32), 1024, 0, stream>>>(x, nsc, nbi, xnT,
                                                qkvw, qkvwb, projw, projwb);
  k_gemm<0><<<dim3(8, 12, 32), 256, 0, stream>>>(qkvwb, xnT, qkvb, nullptr,
                                                 qT, kTb, vb, nullptr);
  k_attn<<<dim3(256, 4), 512, 0, stream>>>(qT, kTb, vb, aoT);
  k_gemm<1><<<dim3(8, 4, 32), 256, 0, stream>>>(projwb, aoT, projb, x,
                                                nullptr, nullptr, nullptr, out);
}